// Round 6
// baseline (5695.758 us; speedup 1.0000x reference)
//
#include <hip/hip_runtime.h>
#include <hip/hip_bf16.h>

// BiGRU: S=512, B=64, I=1024, H=512, bidirectional.
// (1) cast x, Wx to bf16; (2) MFMA GEMM xg = x@Wx; (3) persistent recurrence as
// flagless SENTINEL DATAFLOW: h/rh in depth-4 rings pre-filled with bf16-NaN
// sentinel 0x7FC0. Producers publish 8B pieces with relaxed agent-scope stores
// (sc1, proven transport from R4); consumers retry sc1 16B loads until no piece
// is sentinel. No flags, no barriers, no __syncthreads in the loop, no placement
// assumptions. 32 blocks = 2 dirs x 16 col-slices (32 cols, 96KB LDS weights);
// sync groups are (dir,batch-tile) = 16 waves -> 8 independent chains.

typedef __attribute__((ext_vector_type(8))) short short8;   // 8 x bf16
typedef __attribute__((ext_vector_type(4))) float f32x4;

#define SENT 0x7FC0
#define SENT64 0x7FC07FC07FC07FC0ULL

__device__ __forceinline__ unsigned short f2bf(float f) {
    unsigned u = __builtin_bit_cast(unsigned, f);
    u += 0x7FFFu + ((u >> 16) & 1u);           // RNE
    return (unsigned short)(u >> 16);
}
__device__ __forceinline__ float bf2f(unsigned short h) {
    unsigned u = ((unsigned)h) << 16;
    return __builtin_bit_cast(float, u);
}

// ---------------- converts ----------------

__global__ __launch_bounds__(256) void k_cvt_x(const float* __restrict__ x,
                                               unsigned short* __restrict__ xb) {
    size_t gid = (size_t)blockIdx.x * 256 + threadIdx.x;
    f32x4 a = ((const f32x4*)x)[gid * 2];
    f32x4 b = ((const f32x4*)x)[gid * 2 + 1];
    short8 o;
    o[0] = (short)f2bf(a[0]); o[1] = (short)f2bf(a[1]);
    o[2] = (short)f2bf(a[2]); o[3] = (short)f2bf(a[3]);
    o[4] = (short)f2bf(b[0]); o[5] = (short)f2bf(b[1]);
    o[6] = (short)f2bf(b[2]); o[7] = (short)f2bf(b[3]);
    ((short8*)xb)[gid] = o;
}

__global__ __launch_bounds__(256) void k_cvt_w(const float* __restrict__ Wxf,
                                               const float* __restrict__ Wxb,
                                               unsigned short* __restrict__ wt) {
    int gid = blockIdx.x * 256 + threadIdx.x;   // 393216
    int n = gid >> 7, kc = gid & 127;
    const float* src = (n < 1536) ? Wxf : Wxb;
    int nn = (n >= 1536) ? n - 1536 : n;
    int g = nn >> 9, h = nn & 511;
    short8 o;
#pragma unroll
    for (int j = 0; j < 8; ++j)
        o[j] = (short)f2bf(src[(size_t)(g * 1024 + kc * 8 + j) * 512 + h]);
    *(short8*)(wt + (size_t)n * 1024 + kc * 8) = o;
}

// whsl[d][w][g][c][k] = Wh_d[g][k][w*32+c], w in 0..15, c in 0..31
__global__ __launch_bounds__(256) void k_cvt_whsl(const float* __restrict__ Whf,
                                                  const float* __restrict__ Whb,
                                                  unsigned short* __restrict__ o) {
    int gid = blockIdx.x * 256 + threadIdx.x;   // 196608
    int kc = gid & 63;
    int r = gid >> 6;           // 3072
    int c = r & 31; r >>= 5;    // 96
    int g = r % 3;  r /= 3;     // 32
    int w = r & 15, d = r >> 4;
    const float* src = d ? Whb : Whf;
    short8 v;
#pragma unroll
    for (int j = 0; j < 8; ++j)
        v[j] = (short)f2bf(src[(size_t)(g * 512 + kc * 8 + j) * 512 + w * 32 + c]);
    *(short8*)(o + ((size_t)(((d * 16 + w) * 3 + g) * 32 + c)) * 512 + kc * 8) = v;
}

// fill both rings with the sentinel pattern (done every launch, before k_init)
__global__ __launch_bounds__(256) void k_sent(unsigned short* __restrict__ h4,
                                              unsigned short* __restrict__ rh4) {
    int gid = blockIdx.x * 256 + threadIdx.x;   // 32768 threads x 16B per ring
    short8 s;
#pragma unroll
    for (int j = 0; j < 8; ++j) s[j] = (short)SENT;
    ((short8*)h4)[gid] = s;
    ((short8*)rh4)[gid] = s;
}

// hring slot 0 <- bf16(initial_state)
__global__ __launch_bounds__(256) void k_init(const float* __restrict__ h0,
                                              unsigned short* __restrict__ h4) {
    int gid = blockIdx.x * 256 + threadIdx.x;   // 65536
    int b = gid >> 10, ch = gid & 1023;
    int d = ch >> 9, k = ch & 511;
    h4[((size_t)d * 64 + b) * 512 + k] = f2bf(h0[gid]);
}

// ---------------- GEMM: xg[m][n] = sum_k x[m][k] * Wt[n][k] ----------------

__global__ __launch_bounds__(256) void k_gemm(const unsigned short* __restrict__ A,
                                              const unsigned short* __restrict__ Bt,
                                              unsigned short* __restrict__ C) {
    __shared__ unsigned short Al[128 * 40];
    __shared__ unsigned short Bl[128 * 40];
    const int n0 = blockIdx.x * 128;
    const int m0 = blockIdx.y * 128;
    const int t = threadIdx.x, wave = t >> 6, lane = t & 63;
    const int lg = lane >> 4, lr = lane & 15;
    const int wm = wave >> 1, wn = wave & 1;
    const int lrow = t >> 2, lkb = t & 3;

    f32x4 acc[4][4] = {};
    for (int kt = 0; kt < 32; ++kt) {
        const int k0 = kt * 32;
#pragma unroll
        for (int p = 0; p < 2; ++p) {
            int row = lrow + p * 64;
            *(short8*)(Al + row * 40 + lkb * 8) =
                *(const short8*)(A + (size_t)(m0 + row) * 1024 + k0 + lkb * 8);
            *(short8*)(Bl + row * 40 + lkb * 8) =
                *(const short8*)(Bt + (size_t)(n0 + row) * 1024 + k0 + lkb * 8);
        }
        __syncthreads();
        short8 af[4], bfr[4];
#pragma unroll
        for (int mi = 0; mi < 4; ++mi)
            af[mi] = *(const short8*)(Al + (wm * 64 + mi * 16 + lr) * 40 + lg * 8);
#pragma unroll
        for (int ni = 0; ni < 4; ++ni)
            bfr[ni] = *(const short8*)(Bl + (wn * 64 + ni * 16 + lr) * 40 + lg * 8);
#pragma unroll
        for (int mi = 0; mi < 4; ++mi)
#pragma unroll
            for (int ni = 0; ni < 4; ++ni)
                acc[mi][ni] = __builtin_amdgcn_mfma_f32_16x16x32_bf16(af[mi], bfr[ni],
                                                                      acc[mi][ni], 0, 0, 0);
        __syncthreads();
    }
#pragma unroll
    for (int mi = 0; mi < 4; ++mi)
#pragma unroll
        for (int ni = 0; ni < 4; ++ni) {
            int m = m0 + wm * 64 + mi * 16 + lg * 4;
            int n = n0 + wn * 64 + ni * 16 + lr;
#pragma unroll
            for (int jj = 0; jj < 4; ++jj)
                C[(size_t)(m + jj) * 3072 + n] = f2bf(acc[mi][ni][jj]);
        }
}

// ---------------- sentinel-retry fragment fetch (agent scope, sc1) ----------------

__device__ __forceinline__ void wait_frag(const char* p, short8* fr) {
    for (;;) {
        asm volatile(
            "global_load_dwordx4 %0, %16, off sc1\n\t"
            "global_load_dwordx4 %1, %16, off offset:64 sc1\n\t"
            "global_load_dwordx4 %2, %16, off offset:128 sc1\n\t"
            "global_load_dwordx4 %3, %16, off offset:192 sc1\n\t"
            "global_load_dwordx4 %4, %16, off offset:256 sc1\n\t"
            "global_load_dwordx4 %5, %16, off offset:320 sc1\n\t"
            "global_load_dwordx4 %6, %16, off offset:384 sc1\n\t"
            "global_load_dwordx4 %7, %16, off offset:448 sc1\n\t"
            "global_load_dwordx4 %8, %16, off offset:512 sc1\n\t"
            "global_load_dwordx4 %9, %16, off offset:576 sc1\n\t"
            "global_load_dwordx4 %10, %16, off offset:640 sc1\n\t"
            "global_load_dwordx4 %11, %16, off offset:704 sc1\n\t"
            "global_load_dwordx4 %12, %16, off offset:768 sc1\n\t"
            "global_load_dwordx4 %13, %16, off offset:832 sc1\n\t"
            "global_load_dwordx4 %14, %16, off offset:896 sc1\n\t"
            "global_load_dwordx4 %15, %16, off offset:960 sc1"
            : "=v"(fr[0]), "=v"(fr[1]), "=v"(fr[2]), "=v"(fr[3]),
              "=v"(fr[4]), "=v"(fr[5]), "=v"(fr[6]), "=v"(fr[7]),
              "=v"(fr[8]), "=v"(fr[9]), "=v"(fr[10]), "=v"(fr[11]),
              "=v"(fr[12]), "=v"(fr[13]), "=v"(fr[14]), "=v"(fr[15])
            : "v"(p) : "memory");
        asm volatile("s_waitcnt vmcnt(0)" ::: "memory");
        int bad = 0;
#pragma unroll
        for (int i = 0; i < 16; ++i)
            bad |= (((unsigned short)fr[i][0]) == SENT) |
                   (((unsigned short)fr[i][4]) == SENT);
        if (!__any(bad)) break;
        __builtin_amdgcn_s_sleep(2);
    }
    __builtin_amdgcn_sched_barrier(0);   // rule 18: pin MFMA behind the waitcnt
}

// ---------------- persistent recurrence (flagless dataflow) ----------------
// 32 blocks: d = blk>>4, w = blk&15 (32 cols). Wave = batch-tile (16 rows).
// Thread (wave,lg,lr): b = wave*16+lr, cols cc = w*32 + ct*16 + lg*4 (ct=0,1).
// Rings: h[slot][d][b][k], rh same; slot = it&3, 131072 B per slot.

__global__ __launch_bounds__(256) void k_rec(const unsigned short* __restrict__ xg,
                                             const unsigned short* __restrict__ whsl,
                                             const float* __restrict__ h0,
                                             const float* __restrict__ b_f,
                                             const float* __restrict__ b_b,
                                             unsigned long long* h4,
                                             unsigned long long* rh4,
                                             float* __restrict__ out) {
    __shared__ unsigned short Wl[3 * 32 * 512];   // 96KB [g][c][k], XOR-swizzled

    const int blk = blockIdx.x;
    const int d = blk >> 4, w = blk & 15;
    const int t = threadIdx.x;
    const int wave = t >> 6, lane = t & 63;
    const int lg = lane >> 4, lr = lane & 15;

    {   // stage weights (swizzle: byte ^= ((byte>>10)&7)<<4)
        const char* wsrc = (const char*)(whsl + (size_t)(d * 16 + w) * (3 * 32 * 512));
#pragma unroll
        for (int i = 0; i < 24; ++i) {
            int byte = (t + i * 256) << 4;
            int swz = byte ^ (((byte >> 10) & 7) << 4);
            *(short8*)((char*)Wl + swz) = *(const short8*)(wsrc + byte);
        }
    }
    __syncthreads();   // only block-wide sync in the kernel

    const float* bias = d ? b_b : b_f;
    const int b = wave * 16 + lr;
    const int cswz = (lr & 7) << 4;

    f32x4 bR[2], bU[2], bC[2];
    float h_own[2][4];
#pragma unroll
    for (int ct = 0; ct < 2; ++ct) {
        int cc = w * 32 + ct * 16 + lg * 4;
        bR[ct] = *(const f32x4*)(bias + cc);
        bU[ct] = *(const f32x4*)(bias + 512 + cc);
        bC[ct] = *(const f32x4*)(bias + 1024 + cc);
        f32x4 v = *(const f32x4*)(h0 + (size_t)b * 1024 + d * 512 + cc);
#pragma unroll
        for (int jj = 0; jj < 4; ++jj) h_own[ct][jj] = v[jj];
    }

    const size_t SLOT = 131072;                          // bytes per ring slot
    const size_t rowoff = ((size_t)d * 64 + b) * 1024;   // row base within slot
    char* hb = (char*)h4;
    char* rb = (char*)rh4;
    const int fro  = lg * 16;           // fragment byte offset within row
    const int pubo = w * 64 + lg * 8;   // publish byte offset (+ ct*32)

    // prefetch xg for it = 0
    unsigned long long xR[2], xU[2], xC[2];
    {
        const unsigned short* xp = xg + (size_t)(d ? 511 : 0) * (64 * 3072) +
                                   (size_t)b * 3072 + d * 1536 + w * 32 + lg * 4;
#pragma unroll
        for (int ct = 0; ct < 2; ++ct) {
            xR[ct] = *(const unsigned long long*)(xp + ct * 16);
            xU[ct] = *(const unsigned long long*)(xp + 512 + ct * 16);
            xC[ct] = *(const unsigned long long*)(xp + 1024 + ct * 16);
        }
    }

    for (int it = 0; it < 512; ++it) {
        const int s = d ? (511 - it) : it;
        const size_t slot  = (size_t)(it & 3) * SLOT;
        const size_t oslot = (size_t)((it + 3) & 3) * SLOT;   // slot of h/rh[it-1]

        // ---- phase 1: wait for h[it] fragments ----
        short8 fr[16];
        wait_frag(hb + slot + rowoff + fro, fr);

        // prefetch next step's xg (completes under phase-2 wait)
        unsigned long long nR[2], nU[2], nC[2];
        if (it + 1 < 512) {
            const unsigned short* xp = xg + (size_t)(d ? 510 - it : it + 1) * (64 * 3072) +
                                       (size_t)b * 3072 + d * 1536 + w * 32 + lg * 4;
#pragma unroll
            for (int ct = 0; ct < 2; ++ct) {
                nR[ct] = *(const unsigned long long*)(xp + ct * 16);
                nU[ct] = *(const unsigned long long*)(xp + 512 + ct * 16);
                nC[ct] = *(const unsigned long long*)(xp + 1024 + ct * 16);
            }
        }

        // ---- re-sentinel my pieces of slot (it-1): provably consumed by all ----
#pragma unroll
        for (int ct = 0; ct < 2; ++ct) {
            __hip_atomic_store((unsigned long long*)(hb + oslot + rowoff + pubo + ct * 32),
                               SENT64, __ATOMIC_RELAXED, __HIP_MEMORY_SCOPE_AGENT);
            __hip_atomic_store((unsigned long long*)(rb + oslot + rowoff + pubo + ct * 32),
                               SENT64, __ATOMIC_RELAXED, __HIP_MEMORY_SCOPE_AGENT);
        }

        // ---- phase 1 MFMA: r,u preacts (preact^T = Wh^T . h^T) ----
        f32x4 aR[2] = {{0,0,0,0},{0,0,0,0}}, aU[2] = {{0,0,0,0},{0,0,0,0}};
#pragma unroll
        for (int ks = 0; ks < 16; ++ks) {
            int koff = ks * 64 + lg * 16;
#pragma unroll
            for (int ct = 0; ct < 2; ++ct) {
                short8 w0 = *(const short8*)((const char*)Wl +
                            ((((ct * 16 + lr) << 10) + koff) ^ cswz));
                short8 w1 = *(const short8*)((const char*)Wl +
                            ((((32 + ct * 16 + lr) << 10) + koff) ^ cswz));
                aR[ct] = __builtin_amdgcn_mfma_f32_16x16x32_bf16(w0, fr[ks], aR[ct], 0, 0, 0);
                aU[ct] = __builtin_amdgcn_mfma_f32_16x16x32_bf16(w1, fr[ks], aU[ct], 0, 0, 0);
            }
        }
        float uu[2][4];
#pragma unroll
        for (int ct = 0; ct < 2; ++ct) {
            unsigned long long rhp = 0;
#pragma unroll
            for (int jj = 0; jj < 4; ++jj) {
                float pr = aR[ct][jj] + bf2f((unsigned short)(xR[ct] >> (16 * jj))) + bR[ct][jj];
                float pu = aU[ct][jj] + bf2f((unsigned short)(xU[ct] >> (16 * jj))) + bU[ct][jj];
                float r = 1.f / (1.f + __expf(-pr));
                uu[ct][jj] = 1.f / (1.f + __expf(-pu));
                rhp |= (unsigned long long)f2bf(r * h_own[ct][jj]) << (16 * jj);
            }
            __hip_atomic_store((unsigned long long*)(rb + slot + rowoff + pubo + ct * 32),
                               rhp, __ATOMIC_RELAXED, __HIP_MEMORY_SCOPE_AGENT);
        }

        // ---- phase 2: wait for rh[it] fragments ----
        short8 gr[16];
        wait_frag(rb + slot + rowoff + fro, gr);

        f32x4 aC[2] = {{0,0,0,0},{0,0,0,0}};
#pragma unroll
        for (int ks = 0; ks < 16; ++ks) {
            int koff = ks * 64 + lg * 16;
#pragma unroll
            for (int ct = 0; ct < 2; ++ct) {
                short8 w2 = *(const short8*)((const char*)Wl +
                            ((((64 + ct * 16 + lr) << 10) + koff) ^ cswz));
                aC[ct] = __builtin_amdgcn_mfma_f32_16x16x32_bf16(w2, gr[ks], aC[ct], 0, 0, 0);
            }
        }
        const size_t nslot = (size_t)((it + 1) & 3) * SLOT;
#pragma unroll
        for (int ct = 0; ct < 2; ++ct) {
            f32x4 ov;
            unsigned long long hp = 0;
#pragma unroll
            for (int jj = 0; jj < 4; ++jj) {
                float pc = aC[ct][jj] + bf2f((unsigned short)(xC[ct] >> (16 * jj))) + bC[ct][jj];
                float e = __expf(-2.f * pc);
                float c = 2.f / (1.f + e) - 1.f;                 // tanh
                float hn = uu[ct][jj] * h_own[ct][jj] + (1.f - uu[ct][jj]) * c;
                h_own[ct][jj] = hn;
                ov[jj] = hn;
                hp |= (unsigned long long)f2bf(hn) << (16 * jj);
            }
            __hip_atomic_store((unsigned long long*)(hb + nslot + rowoff + pubo + ct * 32),
                               hp, __ATOMIC_RELAXED, __HIP_MEMORY_SCOPE_AGENT);
            *(f32x4*)(out + ((size_t)s * 64 + b) * 1024 + d * 512 + w * 32 + ct * 16 + lg * 4) = ov;
        }
        if (it + 1 < 512) {
#pragma unroll
            for (int ct = 0; ct < 2; ++ct) { xR[ct] = nR[ct]; xU[ct] = nU[ct]; xC[ct] = nC[ct]; }
        }
    }

    // final state
#pragma unroll
    for (int ct = 0; ct < 2; ++ct) {
        f32x4 ov = {h_own[ct][0], h_own[ct][1], h_own[ct][2], h_own[ct][3]};
        *(f32x4*)(out + (size_t)33554432 + (size_t)b * 1024 + d * 512 +
                  w * 32 + ct * 16 + lg * 4) = ov;
    }
}

// ---------------- launcher ----------------

extern "C" void kernel_launch(void* const* d_in, const int* in_sizes, int n_in,
                              void* d_out, int out_size, void* d_ws, size_t ws_size,
                              hipStream_t stream) {
    const float* x   = (const float*)d_in[0];
    const float* h0  = (const float*)d_in[1];
    const float* Wxf = (const float*)d_in[2];
    const float* Whf = (const float*)d_in[3];
    const float* bf_ = (const float*)d_in[4];
    const float* Wxb = (const float*)d_in[5];
    const float* Whb = (const float*)d_in[6];
    const float* bb_ = (const float*)d_in[7];
    float* out = (float*)d_out;

    char* ws = (char*)d_ws;
    size_t off = 0;
    auto take = [&](size_t bytes) {
        char* p = ws + off;
        off += (bytes + 255) & ~(size_t)255;
        return p;
    };
    unsigned short* xb   = (unsigned short*)take((size_t)33554432 * 2);          // x bf16
    unsigned short* wt   = (unsigned short*)take((size_t)3072 * 1024 * 2);       // Wx^T bf16
    unsigned short* xgp  = (unsigned short*)take((size_t)32768 * 3072 * 2);      // gates bf16
    unsigned short* whsl = (unsigned short*)take((size_t)2 * 16 * 3 * 32 * 512 * 2);
    unsigned long long* h4  = (unsigned long long*)take((size_t)4 * 131072);     // h ring
    unsigned long long* rh4 = (unsigned long long*)take((size_t)4 * 131072);     // rh ring

    if (off > ws_size) return;

    hipLaunchKernelGGL(k_cvt_x,    dim3(16384),   dim3(256), 0, stream, x, xb);
    hipLaunchKernelGGL(k_cvt_w,    dim3(1536),    dim3(256), 0, stream, Wxf, Wxb, wt);
    hipLaunchKernelGGL(k_cvt_whsl, dim3(768),     dim3(256), 0, stream, Whf, Whb, whsl);
    hipLaunchKernelGGL(k_sent,     dim3(128),     dim3(256), 0, stream,
                       (unsigned short*)h4, (unsigned short*)rh4);
    hipLaunchKernelGGL(k_init,     dim3(256),     dim3(256), 0, stream, h0,
                       (unsigned short*)h4);
    hipLaunchKernelGGL(k_gemm,     dim3(24, 256), dim3(256), 0, stream, xb, wt, xgp);
    hipLaunchKernelGGL(k_rec,      dim3(32),      dim3(256), 0, stream, xgp, whsl, h0,
                       bf_, bb_, h4, rh4, out);
}

// Round 8
// 4881.756 us; speedup vs baseline: 1.1667x; 1.1667x over previous
//
#include <hip/hip_runtime.h>
#include <hip/hip_bf16.h>

// BiGRU: S=512, B=64, I=1024, H=512, bidirectional.
// (1) cast x, Wx to bf16; (2) MFMA GEMM xg = x@Wx writing a per-(step,block)
// contiguous layout; (3) persistent recurrence, sentinel dataflow (R6-proven
// agent-scope sc1 transport), dual-direction interleave per block (each block
// owns 16 cols of BOTH dirs; F1/B1/F2/B2 interleaved so each direction's
// exchange latency hides under the other's compute), plus a dedicated 5th
// prefetcher wave staging xg through LDS so xg's HBM latency never sits inside
// a compute wave's vmcnt(0) drain. R8 fix vs R7: prefetcher xgr offsets are
// BYTES (step stride 393216 B, dir offset 196608 B) — R7 used short strides.

typedef __attribute__((ext_vector_type(8))) short short8;   // 8 x bf16
typedef __attribute__((ext_vector_type(4))) float f32x4;

#define SENT 0x7FC0
#define SENT64 0x7FC07FC07FC07FC0ULL

__device__ __forceinline__ unsigned short f2bf(float f) {
    unsigned u = __builtin_bit_cast(unsigned, f);
    u += 0x7FFFu + ((u >> 16) & 1u);           // RNE
    return (unsigned short)(u >> 16);
}
__device__ __forceinline__ float bf2f(unsigned short h) {
    unsigned u = ((unsigned)h) << 16;
    return __builtin_bit_cast(float, u);
}
__device__ __forceinline__ float xv(unsigned long long p, int jj) {
    return bf2f((unsigned short)(p >> (16 * jj)));
}
__device__ __forceinline__ int imin(int a, int b) { return a < b ? a : b; }

// ---------------- converts ----------------

__global__ __launch_bounds__(256) void k_cvt_x(const float* __restrict__ x,
                                               unsigned short* __restrict__ xb) {
    size_t gid = (size_t)blockIdx.x * 256 + threadIdx.x;
    f32x4 a = ((const f32x4*)x)[gid * 2];
    f32x4 b = ((const f32x4*)x)[gid * 2 + 1];
    short8 o;
    o[0] = (short)f2bf(a[0]); o[1] = (short)f2bf(a[1]);
    o[2] = (short)f2bf(a[2]); o[3] = (short)f2bf(a[3]);
    o[4] = (short)f2bf(b[0]); o[5] = (short)f2bf(b[1]);
    o[6] = (short)f2bf(b[2]); o[7] = (short)f2bf(b[3]);
    ((short8*)xb)[gid] = o;
}

__global__ __launch_bounds__(256) void k_cvt_w(const float* __restrict__ Wxf,
                                               const float* __restrict__ Wxb,
                                               unsigned short* __restrict__ wt) {
    int gid = blockIdx.x * 256 + threadIdx.x;   // 393216
    int n = gid >> 7, kc = gid & 127;
    const float* src = (n < 1536) ? Wxf : Wxb;
    int nn = (n >= 1536) ? n - 1536 : n;
    int g = nn >> 9, h = nn & 511;
    short8 o;
#pragma unroll
    for (int j = 0; j < 8; ++j)
        o[j] = (short)f2bf(src[(size_t)(g * 1024 + kc * 8 + j) * 512 + h]);
    *(short8*)(wt + (size_t)n * 1024 + kc * 8) = o;
}

// whsl[d*32+w][g][c(16)][k(512)] = Wh_d[g][k][w*16+c]
__global__ __launch_bounds__(256) void k_cvt_whsl(const float* __restrict__ Whf,
                                                  const float* __restrict__ Whb,
                                                  unsigned short* __restrict__ o) {
    int gid = blockIdx.x * 256 + threadIdx.x;   // 196608
    int kc = gid & 63;
    int r = gid >> 6;          // 3072
    int c = r & 15; r >>= 4;   // 192
    int g = r % 3;  r /= 3;    // 64
    int w = r & 31, d = r >> 5;
    const float* src = d ? Whb : Whf;
    short8 v;
#pragma unroll
    for (int j = 0; j < 8; ++j)
        v[j] = (short)f2bf(src[(size_t)(g * 512 + kc * 8 + j) * 512 + w * 16 + c]);
    *(short8*)(o + ((size_t)((d * 32 + w) * 3 + g) * 16 + c) * 512 + kc * 8) = v;
}

// fill both rings with sentinel (every launch, before k_init)
__global__ __launch_bounds__(256) void k_sent(unsigned short* __restrict__ h4,
                                              unsigned short* __restrict__ rh4) {
    int gid = blockIdx.x * 256 + threadIdx.x;   // 32768 threads x 16B per ring
    short8 s;
#pragma unroll
    for (int j = 0; j < 8; ++j) s[j] = (short)SENT;
    ((short8*)h4)[gid] = s;
    ((short8*)rh4)[gid] = s;
}

// h ring slot 0 <- bf16(initial_state)
__global__ __launch_bounds__(256) void k_init(const float* __restrict__ h0,
                                              unsigned short* __restrict__ h4) {
    int gid = blockIdx.x * 256 + threadIdx.x;   // 65536
    int b = gid >> 10, ch = gid & 1023;
    int d = ch >> 9, k = ch & 511;
    h4[((size_t)d * 64 + b) * 512 + k] = f2bf(h0[gid]);
}

// ---------------- GEMM: xgr packed layout ----------------
// xgr short index: s*196608 + d*98304 + (h>>4)*3072 + b*48 + ((h>>2)&3)*12
//                  + g*4 + (h&3)
// i.e. per (s,d,block w): 6144 B contiguous: [b][lg][R4 U4 C4] bf16.

__global__ __launch_bounds__(256) void k_gemm(const unsigned short* __restrict__ A,
                                              const unsigned short* __restrict__ Bt,
                                              unsigned short* __restrict__ C) {
    __shared__ unsigned short Al[128 * 40];
    __shared__ unsigned short Bl[128 * 40];
    const int n0 = blockIdx.x * 128;
    const int m0 = blockIdx.y * 128;
    const int t = threadIdx.x, wave = t >> 6, lane = t & 63;
    const int lg = lane >> 4, lr = lane & 15;
    const int wm = wave >> 1, wn = wave & 1;
    const int lrow = t >> 2, lkb = t & 3;

    f32x4 acc[4][4] = {};
    for (int kt = 0; kt < 32; ++kt) {
        const int k0 = kt * 32;
#pragma unroll
        for (int p = 0; p < 2; ++p) {
            int row = lrow + p * 64;
            *(short8*)(Al + row * 40 + lkb * 8) =
                *(const short8*)(A + (size_t)(m0 + row) * 1024 + k0 + lkb * 8);
            *(short8*)(Bl + row * 40 + lkb * 8) =
                *(const short8*)(Bt + (size_t)(n0 + row) * 1024 + k0 + lkb * 8);
        }
        __syncthreads();
        short8 af[4], bfr[4];
#pragma unroll
        for (int mi = 0; mi < 4; ++mi)
            af[mi] = *(const short8*)(Al + (wm * 64 + mi * 16 + lr) * 40 + lg * 8);
#pragma unroll
        for (int ni = 0; ni < 4; ++ni)
            bfr[ni] = *(const short8*)(Bl + (wn * 64 + ni * 16 + lr) * 40 + lg * 8);
#pragma unroll
        for (int mi = 0; mi < 4; ++mi)
#pragma unroll
            for (int ni = 0; ni < 4; ++ni)
                acc[mi][ni] = __builtin_amdgcn_mfma_f32_16x16x32_bf16(af[mi], bfr[ni],
                                                                      acc[mi][ni], 0, 0, 0);
        __syncthreads();
    }
#pragma unroll
    for (int mi = 0; mi < 4; ++mi)
#pragma unroll
        for (int ni = 0; ni < 4; ++ni) {
            int m = m0 + wm * 64 + mi * 16 + lg * 4;
            int n = n0 + wn * 64 + ni * 16 + lr;
            int dd = n >= 1536;
            int nn = n - dd * 1536;
            int g = nn >> 9, h = nn & 511;
            size_t colbase = (size_t)dd * 98304 + (size_t)(h >> 4) * 3072 +
                             (size_t)((h >> 2) & 3) * 12 + g * 4 + (h & 3);
#pragma unroll
            for (int jj = 0; jj < 4; ++jj) {
                int mm = m + jj;
                int s = mm >> 6, brow = mm & 63;
                C[(size_t)s * 196608 + colbase + (size_t)brow * 48] = f2bf(acc[mi][ni][jj]);
            }
        }
}

// ---------------- sentinel-retry fragment fetch (agent scope, sc1) ----------------

__device__ __forceinline__ void wait_frag(const char* p, short8* fr) {
    for (;;) {
        asm volatile(
            "global_load_dwordx4 %0, %16, off sc1\n\t"
            "global_load_dwordx4 %1, %16, off offset:64 sc1\n\t"
            "global_load_dwordx4 %2, %16, off offset:128 sc1\n\t"
            "global_load_dwordx4 %3, %16, off offset:192 sc1\n\t"
            "global_load_dwordx4 %4, %16, off offset:256 sc1\n\t"
            "global_load_dwordx4 %5, %16, off offset:320 sc1\n\t"
            "global_load_dwordx4 %6, %16, off offset:384 sc1\n\t"
            "global_load_dwordx4 %7, %16, off offset:448 sc1\n\t"
            "global_load_dwordx4 %8, %16, off offset:512 sc1\n\t"
            "global_load_dwordx4 %9, %16, off offset:576 sc1\n\t"
            "global_load_dwordx4 %10, %16, off offset:640 sc1\n\t"
            "global_load_dwordx4 %11, %16, off offset:704 sc1\n\t"
            "global_load_dwordx4 %12, %16, off offset:768 sc1\n\t"
            "global_load_dwordx4 %13, %16, off offset:832 sc1\n\t"
            "global_load_dwordx4 %14, %16, off offset:896 sc1\n\t"
            "global_load_dwordx4 %15, %16, off offset:960 sc1"
            : "=v"(fr[0]), "=v"(fr[1]), "=v"(fr[2]), "=v"(fr[3]),
              "=v"(fr[4]), "=v"(fr[5]), "=v"(fr[6]), "=v"(fr[7]),
              "=v"(fr[8]), "=v"(fr[9]), "=v"(fr[10]), "=v"(fr[11]),
              "=v"(fr[12]), "=v"(fr[13]), "=v"(fr[14]), "=v"(fr[15])
            : "v"(p) : "memory");
        asm volatile("s_waitcnt vmcnt(0)" ::: "memory");
        int bad = 0;
#pragma unroll
        for (int i = 0; i < 16; ++i)
            bad |= (((unsigned short)fr[i][0]) == SENT) |
                   (((unsigned short)fr[i][4]) == SENT);
        if (!__any(bad)) break;
        __builtin_amdgcn_s_sleep(2);
    }
    __builtin_amdgcn_sched_barrier(0);   // pin MFMA behind the waitcnt (rule 18)
}

// ---------------- persistent recurrence ----------------
// 32 blocks x 320 threads. Waves 0-3: compute (16 batch rows each, BOTH dirs,
// 16 cols per dir). Wave 4: xg prefetcher (global -> LDS double buffer).
// Per step: waitA(h_f) F1 pub | waitB(h_b) B1 pub | waitC(rh_f) F2 pub+out |
// waitD(rh_b) B2 pub+out. Re-sentinel of X[it-1] after the wait proving all
// consumed it; wait_frag's vmcnt(0) serializes resent stores before later pubs.

__global__ __launch_bounds__(320) void k_rec(const unsigned short* __restrict__ xgr,
                                             const unsigned short* __restrict__ whsl,
                                             const float* __restrict__ h0,
                                             const float* __restrict__ b_f,
                                             const float* __restrict__ b_b,
                                             unsigned long long* h4,
                                             unsigned long long* rh4,
                                             float* __restrict__ out) {
    __shared__ char Wlb[98304];   // [dir][g][c16][k512] bf16, XOR-swizzled halves
    __shared__ char xls[24576];   // [buf2][dir][b][lg][R4 U4 C4] bf16
    __shared__ int xg_ready;
    __shared__ int xg_ack[4];

    const int w = blockIdx.x;
    const int t = threadIdx.x;
    const int wave5 = t >> 6, lane = t & 63;

    if (t == 0) {
        xg_ready = 0;
        xg_ack[0] = xg_ack[1] = xg_ack[2] = xg_ack[3] = 0;
    }
    // stage both dirs' weight slices (swizzle: byte ^= ((byte>>10)&7)<<4)
    for (int i = 0; i < 20; ++i) {
        int c = t + i * 320;
        if (c < 6144) {
            int half = (c >= 3072);
            int byte = (c - half * 3072) << 4;
            int swz = byte ^ (((byte >> 10) & 7) << 4);
            *(short8*)(Wlb + half * 49152 + swz) =
                *(const short8*)((const char*)whsl + (size_t)(half * 32 + w) * 49152 + byte);
        }
    }
    __syncthreads();

    if (wave5 == 4) {
        // -------- prefetcher wave: xg[it] -> LDS buf (it&1) --------
        // BYTE strides: step = 393216, bwd dir offset = 196608, block = 6144.
        for (int it = 0; it < 512; ++it) {
            if (it >= 2) {
                for (;;) {
                    int a0 = __hip_atomic_load(&xg_ack[0], __ATOMIC_RELAXED, __HIP_MEMORY_SCOPE_WORKGROUP);
                    int a1 = __hip_atomic_load(&xg_ack[1], __ATOMIC_RELAXED, __HIP_MEMORY_SCOPE_WORKGROUP);
                    int a2 = __hip_atomic_load(&xg_ack[2], __ATOMIC_RELAXED, __HIP_MEMORY_SCOPE_WORKGROUP);
                    int a3 = __hip_atomic_load(&xg_ack[3], __ATOMIC_RELAXED, __HIP_MEMORY_SCOPE_WORKGROUP);
                    if (imin(imin(a0, a1), imin(a2, a3)) >= it - 1) break;
                    __builtin_amdgcn_s_sleep(1);
                }
            }
            const char* pf = (const char*)xgr + (size_t)it * 393216 +
                             (size_t)w * 6144 + lane * 96;
            const char* pb = (const char*)xgr + (size_t)(511 - it) * 393216 + 196608 +
                             (size_t)w * 6144 + lane * 96;
            short8 vf[6], vb[6];
#pragma unroll
            for (int k = 0; k < 6; ++k) {
                vf[k] = *(const short8*)(pf + k * 16);
                vb[k] = *(const short8*)(pb + k * 16);
            }
            char* dst = xls + (it & 1) * 12288 + lane * 96;
#pragma unroll
            for (int k = 0; k < 6; ++k) {
                *(short8*)(dst + k * 16) = vf[k];
                *(short8*)(dst + 6144 + k * 16) = vb[k];
            }
            __builtin_amdgcn_fence(__ATOMIC_RELEASE, "workgroup");
            if (lane == 0)
                __hip_atomic_store(&xg_ready, it + 1, __ATOMIC_RELAXED, __HIP_MEMORY_SCOPE_WORKGROUP);
        }
        return;
    }

    // -------- compute waves --------
    const int wave = wave5, lg = lane >> 4, lr = lane & 15;
    const int b = wave * 16 + lr;
    const int cc = w * 16 + lg * 4;
    const int cswz = (lr & 7) << 4;

    const f32x4 bRf = *(const f32x4*)(b_f + cc);
    const f32x4 bUf = *(const f32x4*)(b_f + 512 + cc);
    const f32x4 bCf = *(const f32x4*)(b_f + 1024 + cc);
    const f32x4 bRb = *(const f32x4*)(b_b + cc);
    const f32x4 bUb = *(const f32x4*)(b_b + 512 + cc);
    const f32x4 bCb = *(const f32x4*)(b_b + 1024 + cc);

    float hf[4], hbo[4];
#pragma unroll
    for (int jj = 0; jj < 4; ++jj) {
        hf[jj]  = h0[(size_t)b * 1024 + cc + jj];
        hbo[jj] = h0[(size_t)b * 1024 + 512 + cc + jj];
    }

    const size_t rof = (size_t)b * 1024;          // fwd row byte offset in slot
    const size_t rob = (size_t)(64 + b) * 1024;   // bwd row
    const int fro  = lg * 16;
    const int pubo = w * 32 + lg * 8;
    const int xoff = (b * 4 + lg) * 24;
    char* hbP = (char*)h4;
    char* rbP = (char*)rh4;

    for (int it = 0; it < 512; ++it) {
        const size_t slot  = (size_t)(it & 3) << 17;
        const size_t nslot = (size_t)((it + 1) & 3) << 17;
        const size_t oslot = (size_t)((it + 3) & 3) << 17;

        // ---- A: wait h_f[it]; resent h_f[it-1] ----
        short8 fr[16];
        wait_frag(hbP + slot + rof + fro, fr);
        __hip_atomic_store((unsigned long long*)(hbP + oslot + rof + pubo), SENT64,
                           __ATOMIC_RELAXED, __HIP_MEMORY_SCOPE_AGENT);

        // xg[it] from LDS (prefetcher), lgkm path only
        while (__hip_atomic_load(&xg_ready, __ATOMIC_RELAXED, __HIP_MEMORY_SCOPE_WORKGROUP) < it + 1)
            __builtin_amdgcn_s_sleep(1);
        __builtin_amdgcn_fence(__ATOMIC_ACQUIRE, "workgroup");
        const char* xp = xls + (it & 1) * 12288 + xoff;
        const unsigned long long xfR = *(const unsigned long long*)(xp);
        const unsigned long long xfU = *(const unsigned long long*)(xp + 8);
        const unsigned long long xfC = *(const unsigned long long*)(xp + 16);
        const unsigned long long xbR = *(const unsigned long long*)(xp + 6144);
        const unsigned long long xbU = *(const unsigned long long*)(xp + 6144 + 8);
        const unsigned long long xbC = *(const unsigned long long*)(xp + 6144 + 16);

        // ---- F1: r,u fwd ----
        f32x4 aR = {0.f, 0.f, 0.f, 0.f}, aU = {0.f, 0.f, 0.f, 0.f};
#pragma unroll
        for (int ks = 0; ks < 16; ++ks) {
            int koff = ks * 64 + lg * 16;
            short8 w0 = *(const short8*)(Wlb + (((lr << 10) + koff) ^ cswz));
            short8 w1 = *(const short8*)(Wlb + ((16384 + (lr << 10) + koff) ^ cswz));
            aR = __builtin_amdgcn_mfma_f32_16x16x32_bf16(w0, fr[ks], aR, 0, 0, 0);
            aU = __builtin_amdgcn_mfma_f32_16x16x32_bf16(w1, fr[ks], aU, 0, 0, 0);
        }
        float uf[4];
        {
            unsigned long long rhp = 0;
#pragma unroll
            for (int jj = 0; jj < 4; ++jj) {
                float pr = aR[jj] + xv(xfR, jj) + bRf[jj];
                float pu = aU[jj] + xv(xfU, jj) + bUf[jj];
                float r = 1.f / (1.f + __expf(-pr));
                uf[jj] = 1.f / (1.f + __expf(-pu));
                rhp |= (unsigned long long)f2bf(r * hf[jj]) << (16 * jj);
            }
            __hip_atomic_store((unsigned long long*)(rbP + slot + rof + pubo), rhp,
                               __ATOMIC_RELAXED, __HIP_MEMORY_SCOPE_AGENT);
        }

        // ---- B: wait h_b[it]; resent h_b[it-1] ----
        short8 fb[16];
        wait_frag(hbP + slot + rob + fro, fb);
        __hip_atomic_store((unsigned long long*)(hbP + oslot + rob + pubo), SENT64,
                           __ATOMIC_RELAXED, __HIP_MEMORY_SCOPE_AGENT);

        // ---- B1: r,u bwd ----
        f32x4 cR = {0.f, 0.f, 0.f, 0.f}, cU = {0.f, 0.f, 0.f, 0.f};
#pragma unroll
        for (int ks = 0; ks < 16; ++ks) {
            int koff = ks * 64 + lg * 16;
            short8 w0 = *(const short8*)(Wlb + 49152 + (((lr << 10) + koff) ^ cswz));
            short8 w1 = *(const short8*)(Wlb + 49152 + ((16384 + (lr << 10) + koff) ^ cswz));
            cR = __builtin_amdgcn_mfma_f32_16x16x32_bf16(w0, fb[ks], cR, 0, 0, 0);
            cU = __builtin_amdgcn_mfma_f32_16x16x32_bf16(w1, fb[ks], cU, 0, 0, 0);
        }
        float ub[4];
        {
            unsigned long long rhp = 0;
#pragma unroll
            for (int jj = 0; jj < 4; ++jj) {
                float pr = cR[jj] + xv(xbR, jj) + bRb[jj];
                float pu = cU[jj] + xv(xbU, jj) + bUb[jj];
                float r = 1.f / (1.f + __expf(-pr));
                ub[jj] = 1.f / (1.f + __expf(-pu));
                rhp |= (unsigned long long)f2bf(r * hbo[jj]) << (16 * jj);
            }
            __hip_atomic_store((unsigned long long*)(rbP + slot + rob + pubo), rhp,
                               __ATOMIC_RELAXED, __HIP_MEMORY_SCOPE_AGENT);
        }

        // ---- C: wait rh_f[it]; resent rh_f[it-1] ----
        short8 gr[16];
        wait_frag(rbP + slot + rof + fro, gr);
        __hip_atomic_store((unsigned long long*)(rbP + oslot + rof + pubo), SENT64,
                           __ATOMIC_RELAXED, __HIP_MEMORY_SCOPE_AGENT);

        // ---- F2: candidate + blend fwd ----
        f32x4 aC = {0.f, 0.f, 0.f, 0.f};
#pragma unroll
        for (int ks = 0; ks < 16; ++ks) {
            int koff = ks * 64 + lg * 16;
            short8 w2 = *(const short8*)(Wlb + ((32768 + (lr << 10) + koff) ^ cswz));
            aC = __builtin_amdgcn_mfma_f32_16x16x32_bf16(w2, gr[ks], aC, 0, 0, 0);
        }
        {
            f32x4 ov;
            unsigned long long hp = 0;
#pragma unroll
            for (int jj = 0; jj < 4; ++jj) {
                float pc = aC[jj] + xv(xfC, jj) + bCf[jj];
                float e = __expf(-2.f * pc);
                float c = 2.f / (1.f + e) - 1.f;
                float hn = uf[jj] * hf[jj] + (1.f - uf[jj]) * c;
                hf[jj] = hn;
                ov[jj] = hn;
                hp |= (unsigned long long)f2bf(hn) << (16 * jj);
            }
            __hip_atomic_store((unsigned long long*)(hbP + nslot + rof + pubo), hp,
                               __ATOMIC_RELAXED, __HIP_MEMORY_SCOPE_AGENT);
            *(f32x4*)(out + ((size_t)it * 64 + b) * 1024 + cc) = ov;
        }

        // ---- D: wait rh_b[it]; resent rh_b[it-1] ----
        short8 gb[16];
        wait_frag(rbP + slot + rob + fro, gb);
        __hip_atomic_store((unsigned long long*)(rbP + oslot + rob + pubo), SENT64,
                           __ATOMIC_RELAXED, __HIP_MEMORY_SCOPE_AGENT);

        // ---- B2: candidate + blend bwd ----
        f32x4 cC = {0.f, 0.f, 0.f, 0.f};
#pragma unroll
        for (int ks = 0; ks < 16; ++ks) {
            int koff = ks * 64 + lg * 16;
            short8 w2 = *(const short8*)(Wlb + 49152 + ((32768 + (lr << 10) + koff) ^ cswz));
            cC = __builtin_amdgcn_mfma_f32_16x16x32_bf16(w2, gb[ks], cC, 0, 0, 0);
        }
        {
            f32x4 ov;
            unsigned long long hp = 0;
#pragma unroll
            for (int jj = 0; jj < 4; ++jj) {
                float pc = cC[jj] + xv(xbC, jj) + bCb[jj];
                float e = __expf(-2.f * pc);
                float c = 2.f / (1.f + e) - 1.f;
                float hn = ub[jj] * hbo[jj] + (1.f - ub[jj]) * c;
                hbo[jj] = hn;
                ov[jj] = hn;
                hp |= (unsigned long long)f2bf(hn) << (16 * jj);
            }
            __hip_atomic_store((unsigned long long*)(hbP + nslot + rob + pubo), hp,
                               __ATOMIC_RELAXED, __HIP_MEMORY_SCOPE_AGENT);
            *(f32x4*)(out + ((size_t)(511 - it) * 64 + b) * 1024 + 512 + cc) = ov;
        }

        if (lane == 0)
            __hip_atomic_store(&xg_ack[wave], it + 1, __ATOMIC_RELAXED, __HIP_MEMORY_SCOPE_WORKGROUP);
    }

    // final states
    {
        f32x4 of = {hf[0], hf[1], hf[2], hf[3]};
        f32x4 ob = {hbo[0], hbo[1], hbo[2], hbo[3]};
        *(f32x4*)(out + (size_t)33554432 + (size_t)b * 1024 + cc) = of;
        *(f32x4*)(out + (size_t)33554432 + (size_t)b * 1024 + 512 + cc) = ob;
    }
}

// ---------------- launcher ----------------

extern "C" void kernel_launch(void* const* d_in, const int* in_sizes, int n_in,
                              void* d_out, int out_size, void* d_ws, size_t ws_size,
                              hipStream_t stream) {
    const float* x   = (const float*)d_in[0];
    const float* h0  = (const float*)d_in[1];
    const float* Wxf = (const float*)d_in[2];
    const float* Whf = (const float*)d_in[3];
    const float* bf_ = (const float*)d_in[4];
    const float* Wxb = (const float*)d_in[5];
    const float* Whb = (const float*)d_in[6];
    const float* bb_ = (const float*)d_in[7];
    float* out = (float*)d_out;

    char* ws = (char*)d_ws;
    size_t off = 0;
    auto take = [&](size_t bytes) {
        char* p = ws + off;
        off += (bytes + 255) & ~(size_t)255;
        return p;
    };
    unsigned short* xb   = (unsigned short*)take((size_t)33554432 * 2);          // x bf16
    unsigned short* wt   = (unsigned short*)take((size_t)3072 * 1024 * 2);       // Wx^T bf16
    unsigned short* xgr  = (unsigned short*)take((size_t)512 * 196608 * 2);      // packed gates
    unsigned short* whsl = (unsigned short*)take((size_t)2 * 32 * 3 * 16 * 512 * 2);
    unsigned long long* h4  = (unsigned long long*)take((size_t)4 * 131072);     // h ring
    unsigned long long* rh4 = (unsigned long long*)take((size_t)4 * 131072);     // rh ring

    if (off > ws_size) return;

    hipLaunchKernelGGL(k_cvt_x,    dim3(16384),   dim3(256), 0, stream, x, xb);
    hipLaunchKernelGGL(k_cvt_w,    dim3(1536),    dim3(256), 0, stream, Wxf, Wxb, wt);
    hipLaunchKernelGGL(k_cvt_whsl, dim3(768),     dim3(256), 0, stream, Whf, Whb, whsl);
    hipLaunchKernelGGL(k_sent,     dim3(128),     dim3(256), 0, stream,
                       (unsigned short*)h4, (unsigned short*)rh4);
    hipLaunchKernelGGL(k_init,     dim3(256),     dim3(256), 0, stream, h0,
                       (unsigned short*)h4);
    hipLaunchKernelGGL(k_gemm,     dim3(24, 256), dim3(256), 0, stream, xb, wt, xgr);
    hipLaunchKernelGGL(k_rec,      dim3(32),      dim3(320), 0, stream, xgr, whsl, h0,
                       bf_, bb_, h4, rh4, out);
}